// Round 3
// baseline (2924.253 us; speedup 1.0000x reference)
//
#include <hip/hip_runtime.h>

// File-scope: forbid implicit fma contraction (keeps every a*b+c as two
// single-rounded IEEE ops, matching the numpy reference bit-for-bit).
#pragma clang fp contract(off)

#define NPOINT 2048
#define NSAMPLE 32
#define NPTS 8192
#define NB 4
#define CH 16
#define FPS_THREADS 512
#define PTS_PER_THREAD (NPTS / FPS_THREADS) /* 16 */
#define PAIRS (PTS_PER_THREAD / 2)          /* 8 */
#define FPS_WAVES (FPS_THREADS / 64)        /* 8 */

typedef unsigned long long u64;
typedef float v2f __attribute__((ext_vector_type(2)));

// Output layout (flat float32, concatenated in reference return order)
#define OFF_NEWXYZ 0
#define OFF_NEWPTS (NB * NPOINT * 3)                          /* 24576 */
#define OFF_IDX (OFF_NEWPTS + NB * NPOINT * NSAMPLE * CH)     /* 4218880 */
#define OFF_GXYZ (OFF_IDX + NB * NPOINT * NSAMPLE)            /* 4481024 */

template <int CTRL>
__device__ __forceinline__ float dpp_fmax(float v) {
  // bound_ctrl=true -> 0-fill; distances are >= 0 so 0 is a safe identity.
  int o = __builtin_amdgcn_update_dpp(0, __float_as_int(v), CTRL, 0xf, 0xf, true);
  return fmaxf(v, __int_as_float(o));
}

// ---------------- FPS: one block per batch, sequential 2048-step scan ------
// Reference semantics: idxs[0]=0; each step: dists=min(dists,|p-p_last|^2),
// next = argmax(dists) with FIRST-index tie-break. Op order mirrored:
// (dx*dx + dy*dy) + dz*dz, single-rounded IEEE, no fma contraction.
//
// R20: coords-in-slot. Occupancy axis exhausted (1024t=1910, 512t=1735,
// 256t=2120 w/ VGPR squeeze); VALUBusy(gfx94x formula, 4cy/instr) halves on
// SIMD-32 -> true issue ~37%: the 512t kernel is LATENCY-bound. Dominant
// removable link: the dependent lpxyz[gi] ds_read (~140cy) after the key
// tree. Fix: each wave publishes its winner's COORDS (float4) next to its
// key; readers load keys + all coord slots in ONE latency window, then
// select the winner's coords with a 2-bit cndmask tree. Winning wave index
// is free: contiguous ownership -> ws = besti >> 10. This also deletes the
// 128KB lpxyz array entirely (its only reader was that load): LDS 156->25KB.
// Coord tracking in-loop (+6 cndmask/pair) rides the same strict-'>' predicate
// as bestjp -> published coords are bit-exact input copies of point besti.
//  - winner lane ds_write_b64 key + ds_write_b128 coords; next iter all
//    threads read 8 keys (4 b128) + 8 coord slots (8 b128), 7-compare u64
//    max. Parity double-buffer, one barrier/iter.
//  - in-loop tracking fused for v_max3: nb=fmax(fmax(dn.x,dn.y),bestv);
//    (nb>bestv) is the identical strict predicate; bestv=nb same value.
//  - post-loop parity resolve: bestj = 2*bestjp + (bestx==bestv ? 0 : 1).
// Tie-breaks (exact jnp.argmax lowest-index): parity checks .x first; strict
// '>' keeps lowest jp; ballot-ctz keeps lowest lane; key low word (8191-idx)
// keeps lowest wave. Contiguous ownership (thread t owns t*16..t*16+15)
// keeps (wave,lane,j) order == global index order. Keys are globally unique
// (idx in low bits) so the u64 max has no cross-wave ties.
__global__ __launch_bounds__(FPS_THREADS)
__attribute__((amdgpu_waves_per_eu(2))) void fps_kernel(
    const float* __restrict__ in, float* __restrict__ out) {
  __shared__ float newb[NPOINT * 3];               // 24 KB newxyz staging
  __shared__ alignas(16) u64 slots_k[2][FPS_WAVES];    // per-wave argmax keys
  __shared__ alignas(16) float4 slots_c[2][FPS_WAVES]; // per-wave winner coords

  const int b = blockIdx.x;
  const int tid = threadIdx.x;
  const int lane = tid & 63;
  const int wv = tid >> 6;
  const float* base = in + (size_t)b * NPTS * CH;

  v2f pxv[PAIRS], pyv[PAIRS], pzv[PAIRS], dv[PAIRS];
#pragma unroll
  for (int jp = 0; jp < PAIRS; ++jp) {
    int p0 = tid * PTS_PER_THREAD + 2 * jp;
    float4 r0 = *reinterpret_cast<const float4*>(base + (size_t)p0 * CH);
    float4 r1 = *reinterpret_cast<const float4*>(base + (size_t)(p0 + 1) * CH);
    pxv[jp] = (v2f){r0.x, r1.x};
    pyv[jp] = (v2f){r0.y, r1.y};
    pzv[jp] = (v2f){r0.z, r1.z};
    dv[jp] = (v2f){__builtin_inff(), __builtin_inff()};
  }
  // Prime parity-0: slot 0 = (+inf, idx 0) wins iteration 0; its coords are
  // point 0's (re-read from global, L2-hot). Dummy slots lose (key 0).
  if (tid < FPS_WAVES) {
    slots_k[0][tid] = (tid == 0) ? (((u64)0x7f800000u << 32) | 8191u) : 0ull;
    slots_k[1][tid] = 0ull;
    slots_c[0][tid] = make_float4(0.f, 0.f, 0.f, 0.f);
    slots_c[1][tid] = make_float4(0.f, 0.f, 0.f, 0.f);
  }
  if (tid == 0)
    slots_c[0][0] = make_float4(base[0], base[1], base[2], 0.f);

  for (int it = 0; it < NPOINT; ++it) {
    __syncthreads();  // separates slot writes (it-1) from reads (it)
    const int par = it & 1;
    // Keys (4x b128) + all 8 coord slots (8x b128): one latency window.
    const ulonglong2* sp =
        reinterpret_cast<const ulonglong2*>(&slots_k[par][0]);
    const ulonglong2 s01 = sp[0];
    const ulonglong2 s23 = sp[1];
    const ulonglong2 s45 = sp[2];
    const ulonglong2 s67 = sp[3];
    const float4 c0 = slots_c[par][0];
    const float4 c1 = slots_c[par][1];
    const float4 c2 = slots_c[par][2];
    const float4 c3 = slots_c[par][3];
    const float4 c4 = slots_c[par][4];
    const float4 c5 = slots_c[par][5];
    const float4 c6 = slots_c[par][6];
    const float4 c7 = slots_c[par][7];
    // 7-compare u64 max (keys globally unique -> no ties).
    u64 ka = (s01.y > s01.x) ? s01.y : s01.x;
    u64 kb = (s23.y > s23.x) ? s23.y : s23.x;
    u64 kc = (s45.y > s45.x) ? s45.y : s45.x;
    u64 kd = (s67.y > s67.x) ? s67.y : s67.x;
    ka = (kb > ka) ? kb : ka;
    kc = (kd > kc) ? kd : kc;
    const u64 k = (kc > ka) ? kc : ka;
    // Winner wave = owner wave of the winning point (contiguous ownership).
    const unsigned gi = 8191u - (unsigned)k;  // low 32 bits = 8191-idx
    const unsigned ws = gi >> 10;             // 1024 points per wave
    const bool b0 = (ws & 1u) != 0u;
    const bool b1 = (ws & 2u) != 0u;
    const bool b2 = (ws & 4u) != 0u;
    const float gx =
        b2 ? (b1 ? (b0 ? c7.x : c6.x) : (b0 ? c5.x : c4.x))
           : (b1 ? (b0 ? c3.x : c2.x) : (b0 ? c1.x : c0.x));
    const float gy =
        b2 ? (b1 ? (b0 ? c7.y : c6.y) : (b0 ? c5.y : c4.y))
           : (b1 ? (b0 ? c3.y : c2.y) : (b0 ? c1.y : c0.y));
    const float gz =
        b2 ? (b1 ? (b0 ? c7.z : c6.z) : (b0 ? c5.z : c4.z))
           : (b1 ? (b0 ? c3.z : c2.z) : (b0 ? c1.z : c0.z));
    if (tid == 0) {
      newb[it * 3 + 0] = gx;
      newb[it * 3 + 1] = gy;
      newb[it * 3 + 2] = gz;
    }
    if (it == NPOINT - 1) break;  // last winner staged; update/publish useless
    // Distance update (packed pairs; exact IEEE per-element) + in-loop
    // pair-granular tracking. nb = max3(dn.x, dn.y, bestv): (nb > bestv)
    // == (fmax(dn.x,dn.y) > bestv) exactly, and bestv=nb is the same value.
    float bestv = -1.0f;
    float bestx = -1.0f;
    int bestjp = 0;
    v2f bpx = pxv[0], bpy = pyv[0], bpz = pzv[0];
#pragma unroll
    for (int jp = 0; jp < PAIRS; ++jp) {
      v2f dx = pxv[jp] - gx;
      v2f dy = pyv[jp] - gy;
      v2f dz = pzv[jp] - gz;
      v2f nd = (dx * dx + dy * dy) + dz * dz;
      v2f dn = {fminf(dv[jp].x, nd.x), fminf(dv[jp].y, nd.y)};
      dv[jp] = dn;
      float nb = fmaxf(fmaxf(dn.x, dn.y), bestv);  // -> v_max3_f32
      bool t = nb > bestv;  // strict: lowest jp wins ties
      bestjp = t ? jp : bestjp;
      bestx = t ? dn.x : bestx;
      bpx = t ? pxv[jp] : bpx;  // candidate coords ride the same predicate
      bpy = t ? pyv[jp] : bpy;
      bpz = t ? pzv[jp] : bpz;
      bestv = nb;
    }
    // Within-pair parity: .x first (lower index) on ties.
    const bool selx = (bestx == bestv);
    const int bestj = 2 * bestjp + (selx ? 0 : 1);
    const unsigned besti = (unsigned)(tid * PTS_PER_THREAD + bestj);
    const float wx = selx ? bpx.x : bpx.y;
    const float wy = selx ? bpy.x : bpy.y;
    const float wz = selx ? bpz.x : bpz.y;
    // Wave max via 6 DPP rounds -> lane 63; ballot -> lowest matching lane.
    float wm = bestv;
    wm = dpp_fmax<0x111>(wm);  // row_shr:1
    wm = dpp_fmax<0x112>(wm);  // row_shr:2
    wm = dpp_fmax<0x114>(wm);  // row_shr:4
    wm = dpp_fmax<0x118>(wm);  // row_shr:8
    wm = dpp_fmax<0x142>(wm);  // row_bcast15
    wm = dpp_fmax<0x143>(wm);  // row_bcast31
    const float swm =
        __int_as_float(__builtin_amdgcn_readlane(__float_as_int(wm), 63));
    const u64 wbal = __ballot(bestv == swm);
    const int wl = (int)__builtin_ctzll(wbal);
    if (lane == wl) {  // tiny tail: key b64 + coords b128
      slots_k[par ^ 1][wv] =
          ((u64)__float_as_uint(bestv) << 32) | (8191u - besti);
      slots_c[par ^ 1][wv] = make_float4(wx, wy, wz, 0.f);
    }
  }
  __syncthreads();
  // Dump staged newxyz to global once.
  float* ob = out + OFF_NEWXYZ + (size_t)b * NPOINT * 3;
  for (int i = tid; i < NPOINT * 3; i += FPS_THREADS) ob[i] = newb[i];
}

// ---------------- Ball query + group: one wave per query -------------------
__device__ __forceinline__ void write_slot(float* __restrict__ out,
                                           const float* __restrict__ base,
                                           int b, int qi, int s, int p,
                                           float4 r0, float qx, float qy,
                                           float qz) {
  float dx = __fsub_rn(r0.x, qx);
  float dy = __fsub_rn(r0.y, qy);
  float dz = __fsub_rn(r0.z, qz);
  size_t qs = (size_t)b * NPOINT + qi;
  out[OFF_IDX + qs * NSAMPLE + s] = (float)p;  // idx stored as float32
  float* g = out + OFF_GXYZ + (qs * NSAMPLE + s) * 3;
  g[0] = dx;
  g[1] = dy;
  g[2] = dz;
  const float* row = base + (size_t)p * CH;
  float4 r1 = *reinterpret_cast<const float4*>(row + 4);
  float4 r2 = *reinterpret_cast<const float4*>(row + 8);
  float4 r3 = *reinterpret_cast<const float4*>(row + 12);
  float* np_ = out + OFF_NEWPTS + (qs * NSAMPLE + s) * CH;
  *reinterpret_cast<float4*>(np_ + 0) = make_float4(dx, dy, dz, r0.w);
  *reinterpret_cast<float4*>(np_ + 4) = r1;
  *reinterpret_cast<float4*>(np_ + 8) = r2;
  *reinterpret_cast<float4*>(np_ + 12) = r3;
}

__global__ __launch_bounds__(256) void ballq_kernel(
    const float* __restrict__ in, float* __restrict__ out) {
  const int lane = threadIdx.x & 63;
  const int qid = blockIdx.x * 4 + (threadIdx.x >> 6);
  const int b = qid >> 11;    // / NPOINT
  const int qi = qid & 2047;  // % NPOINT
  const float* base = in + (size_t)b * NPTS * CH;
  const float* q = out + OFF_NEWXYZ + ((size_t)b * NPOINT + qi) * 3;
  float qx = q[0], qy = q[1], qz = q[2];
  // Mirror reference: d2 = sum(q*q) + sum(p*p) - 2*(q . p)
  float qn = __fadd_rn(__fadd_rn(__fmul_rn(qx, qx), __fmul_rn(qy, qy)),
                       __fmul_rn(qz, qz));

  int cnt = 0;
  int first = 0;
  bool have_first = false;
  for (int chunk = 0; chunk < NPTS / 64 && cnt < NSAMPLE; ++chunk) {
    int p = chunk * 64 + lane;
    float4 r0 = *reinterpret_cast<const float4*>(base + (size_t)p * CH);
    float pn =
        __fadd_rn(__fadd_rn(__fmul_rn(r0.x, r0.x), __fmul_rn(r0.y, r0.y)),
                  __fmul_rn(r0.z, r0.z));
    float dot =
        __fadd_rn(__fadd_rn(__fmul_rn(qx, r0.x), __fmul_rn(qy, r0.y)),
                  __fmul_rn(qz, r0.z));
    float d2 = __fsub_rn(__fadd_rn(qn, pn), __fmul_rn(2.0f, dot));
    bool in_r = d2 < 1.0f;  // RADIUS^2
    unsigned long long mask = __ballot(in_r);
    if (!have_first && mask) {
      first = chunk * 64 + __builtin_ctzll(mask);
      have_first = true;
    }
    int pos = cnt + __popcll(mask & ((1ull << lane) - 1ull));
    if (in_r && pos < NSAMPLE) write_slot(out, base, b, qi, pos, p, r0, qx, qy, qz);
    cnt += __popcll(mask);
  }
  if (cnt < NSAMPLE) {
    // Pad remaining slots with the first in-radius index (reference fill rule).
    int s = cnt + lane;
    if (s < NSAMPLE) {
      float4 r0 = *reinterpret_cast<const float4*>(base + (size_t)first * CH);
      write_slot(out, base, b, qi, s, first, r0, qx, qy, qz);
    }
  }
}

extern "C" void kernel_launch(void* const* d_in, const int* in_sizes, int n_in,
                              void* d_out, int out_size, void* d_ws,
                              size_t ws_size, hipStream_t stream) {
  (void)in_sizes;
  (void)n_in;
  (void)out_size;
  (void)d_ws;
  (void)ws_size;
  const float* in = (const float*)d_in[0];
  float* out = (float*)d_out;
  fps_kernel<<<NB, FPS_THREADS, 0, stream>>>(in, out);
  ballq_kernel<<<(NB * NPOINT) / 4, 256, 0, stream>>>(in, out);
}

// Round 4
// 2208.508 us; speedup vs baseline: 1.3241x; 1.3241x over previous
//
#include <hip/hip_runtime.h>

// File-scope: forbid implicit fma contraction (keeps every a*b+c as two
// single-rounded IEEE ops, matching the numpy reference bit-for-bit).
#pragma clang fp contract(off)

#define NPOINT 2048
#define NSAMPLE 32
#define NPTS 8192
#define NB 4
#define CH 16
#define FPS_THREADS 512
#define PTS_PER_THREAD (NPTS / FPS_THREADS) /* 16 */
#define PAIRS (PTS_PER_THREAD / 2)          /* 8 */
#define FPS_WAVES (FPS_THREADS / 64)        /* 8 */

typedef unsigned long long u64;
typedef float v2f __attribute__((ext_vector_type(2)));

// Output layout (flat float32, concatenated in reference return order)
#define OFF_NEWXYZ 0
#define OFF_NEWPTS (NB * NPOINT * 3)                          /* 24576 */
#define OFF_IDX (OFF_NEWPTS + NB * NPOINT * NSAMPLE * CH)     /* 4218880 */
#define OFF_GXYZ (OFF_IDX + NB * NPOINT * NSAMPLE)            /* 4481024 */

template <int CTRL>
__device__ __forceinline__ float dpp_fmax(float v) {
  // bound_ctrl=true -> 0-fill; distances are >= 0 so 0 is a safe identity.
  int o = __builtin_amdgcn_update_dpp(0, __float_as_int(v), CTRL, 0xf, 0xf, true);
  return fmaxf(v, __int_as_float(o));
}

// Packed f32 math, hand-emitted. hipcc scalarizes v2f arithmetic (R17's
// VALUBusy ~74%/CU matches the 22-op/pair scalar count, not the 14-op packed
// count). v_pk_{add,mul}_f32 are per-element IEEE identical to v_{add,mul}.
// Side benefit: asm-defined values cannot be rematerialized as global
// reloads -> pins px/py/pz/dv in VGPRs (the R19/R20 demotion trigger).
__device__ __forceinline__ v2f pk_add(v2f a, v2f b) {
  v2f d;
  asm("v_pk_add_f32 %0, %1, %2" : "=v"(d) : "v"(a), "v"(b));
  return d;
}
__device__ __forceinline__ v2f pk_mul(v2f a, v2f b) {
  v2f d;
  asm("v_pk_mul_f32 %0, %1, %2" : "=v"(d) : "v"(a), "v"(b));
  return d;
}

// ---------------- FPS: one block per batch, sequential 2048-step scan ------
// Reference semantics: idxs[0]=0; each step: dists=min(dists,|p-p_last|^2),
// next = argmax(dists) with FIRST-index tie-break. Op order mirrored:
// (dx*dx + dy*dy) + dz*dz, single-rounded IEEE, no fma contraction
// (a + (-b) is IEEE subtraction; xor-negation is exact).
//
// R21: exact R17 structure (1735us verified: 512t, 2 waves/SIMD, lpxyz LDS,
// key-slot exchange, one barrier/iter) + inline-asm packed-f32 inner loop.
// R18 (spin-poll) +152us: polling added issue at the detection point.
// R19 (256t) +385us: 1 wave/SIMD exposes all latency + VGPR demotion.
// R20 (coords-in-slot + in-loop coord tracking) +1100us: allocator demoted
// the point arrays to per-iter global reloads (VGPR 88->60 signature).
//  - winner lane ds_write_b64's its key; next iter all threads read 8 keys
//    (4 broadcast b128) + 7-compare u64 max. Parity double-buffer, one
//    barrier/iter.
//  - in-loop tracking fused for v_max3: nb=fmax(fmax(dn.x,dn.y),bestv);
//    (nb>bestv) is the identical strict predicate; bestv=nb same value.
//  - post-loop parity resolve: bestj = 2*bestjp + (bestx==bestv ? 0 : 1).
// Tie-breaks (exact jnp.argmax lowest-index): parity checks .x first; strict
// '>' keeps lowest jp; ballot-ctz keeps lowest lane; key low word (8191-idx)
// keeps lowest wave. Contiguous ownership (thread t owns t*16..t*16+15)
// keeps (wave,lane,j) order == global index order.
__global__ __launch_bounds__(FPS_THREADS)
__attribute__((amdgpu_waves_per_eu(2))) void fps_kernel(
    const float* __restrict__ in, float* __restrict__ out) {
  __shared__ float4 lpxyz[NPTS];      // 128 KB; winner coords: 1 ds_read_b128
  __shared__ float newb[NPOINT * 3];  // 24 KB newxyz staging
  __shared__ alignas(16) u64 slots[2][FPS_WAVES];  // per-wave argmax keys

  const int b = blockIdx.x;
  const int tid = threadIdx.x;
  const int lane = tid & 63;
  const int wv = tid >> 6;
  const float* base = in + (size_t)b * NPTS * CH;

  v2f pxv[PAIRS], pyv[PAIRS], pzv[PAIRS], dv[PAIRS];
#pragma unroll
  for (int jp = 0; jp < PAIRS; ++jp) {
    int p0 = tid * PTS_PER_THREAD + 2 * jp;
    float4 r0 = *reinterpret_cast<const float4*>(base + (size_t)p0 * CH);
    float4 r1 = *reinterpret_cast<const float4*>(base + (size_t)(p0 + 1) * CH);
    pxv[jp] = (v2f){r0.x, r1.x};
    pyv[jp] = (v2f){r0.y, r1.y};
    pzv[jp] = (v2f){r0.z, r1.z};
    lpxyz[p0] = r0;
    lpxyz[p0 + 1] = r1;
    dv[jp] = (v2f){__builtin_inff(), __builtin_inff()};
  }
  // Prime parity-0 slots: slot 0 = (+inf, idx 0) wins the first compare.
  if (tid < FPS_WAVES)
    slots[0][tid] = (tid == 0) ? (((u64)0x7f800000u << 32) | 8191u) : 0ull;

  for (int it = 0; it < NPOINT; ++it) {
    __syncthreads();  // separates slot writes (it-1) from reads (it)
    // Read all 8 wave keys (broadcast, 4x ds_read_b128), 7-compare u64 max.
    const ulonglong2* sp =
        reinterpret_cast<const ulonglong2*>(&slots[it & 1][0]);
    const ulonglong2 s01 = sp[0];
    const ulonglong2 s23 = sp[1];
    const ulonglong2 s45 = sp[2];
    const ulonglong2 s67 = sp[3];
    u64 ka = (s01.y > s01.x) ? s01.y : s01.x;
    u64 kb = (s23.y > s23.x) ? s23.y : s23.x;
    u64 kc = (s45.y > s45.x) ? s45.y : s45.x;
    u64 kd = (s67.y > s67.x) ? s67.y : s67.x;
    ka = (kb > ka) ? kb : ka;
    kc = (kd > kc) ? kd : kc;
    const u64 k = (kc > ka) ? kc : ka;
    const int gi = 8191 - (int)(unsigned)k;  // low 32 bits = 8191-idx
    // Winner coords: broadcast LDS read.
    const float4 g = lpxyz[gi];
    const float gx = g.x, gy = g.y, gz = g.z;
    if (tid == 0) {
      newb[it * 3 + 0] = gx;
      newb[it * 3 + 1] = gy;
      newb[it * 3 + 2] = gz;
    }
    if (it == NPOINT - 1) break;  // last winner staged; update/publish useless
    // Negated winner coords as packed pairs (xor-neg is exact; a+(-b) == a-b).
    const v2f ngx = (v2f){-gx, -gx};
    const v2f ngy = (v2f){-gy, -gy};
    const v2f ngz = (v2f){-gz, -gz};
    // Distance update (packed pairs; exact IEEE per-element) + in-loop
    // pair-granular tracking. nb = max3(dn.x, dn.y, bestv): (nb > bestv)
    // == (fmax(dn.x,dn.y) > bestv) exactly, and bestv=nb is the same value.
    float bestv = -1.0f;
    float bestx = -1.0f;
    int bestjp = 0;
#pragma unroll
    for (int jp = 0; jp < PAIRS; ++jp) {
      v2f dx = pk_add(pxv[jp], ngx);
      v2f dy = pk_add(pyv[jp], ngy);
      v2f dz = pk_add(pzv[jp], ngz);
      v2f xx = pk_mul(dx, dx);
      v2f yy = pk_mul(dy, dy);
      v2f ss = pk_add(xx, yy);
      v2f zz = pk_mul(dz, dz);
      v2f nd = pk_add(ss, zz);  // (dx*dx + dy*dy) + dz*dz, reference order
      v2f dn = {fminf(dv[jp].x, nd.x), fminf(dv[jp].y, nd.y)};
      dv[jp] = dn;
      float nb = fmaxf(fmaxf(dn.x, dn.y), bestv);  // -> v_max3_f32
      bool t = nb > bestv;  // strict: lowest jp wins ties
      bestjp = t ? jp : bestjp;
      bestx = t ? dn.x : bestx;
      bestv = nb;
    }
    // Within-pair parity: .x first (lower index) on ties.
    const int bestj = 2 * bestjp + ((bestx == bestv) ? 0 : 1);
    const unsigned besti = (unsigned)(tid * PTS_PER_THREAD + bestj);
    // Wave max via 6 DPP rounds -> lane 63; ballot -> lowest matching lane.
    float wm = bestv;
    wm = dpp_fmax<0x111>(wm);  // row_shr:1
    wm = dpp_fmax<0x112>(wm);  // row_shr:2
    wm = dpp_fmax<0x114>(wm);  // row_shr:4
    wm = dpp_fmax<0x118>(wm);  // row_shr:8
    wm = dpp_fmax<0x142>(wm);  // row_bcast15
    wm = dpp_fmax<0x143>(wm);  // row_bcast31
    const float swm =
        __int_as_float(__builtin_amdgcn_readlane(__float_as_int(wm), 63));
    const u64 wbal = __ballot(bestv == swm);
    const int wl = (int)__builtin_ctzll(wbal);
    if (lane == wl) {  // tiny tail: pack + one ds_write_b64
      slots[(it + 1) & 1][wv] =
          ((u64)__float_as_uint(bestv) << 32) | (8191u - besti);
    }
  }
  __syncthreads();
  // Dump staged newxyz to global once.
  float* ob = out + OFF_NEWXYZ + (size_t)b * NPOINT * 3;
  for (int i = tid; i < NPOINT * 3; i += FPS_THREADS) ob[i] = newb[i];
}

// ---------------- Ball query + group: one wave per query -------------------
__device__ __forceinline__ void write_slot(float* __restrict__ out,
                                           const float* __restrict__ base,
                                           int b, int qi, int s, int p,
                                           float4 r0, float qx, float qy,
                                           float qz) {
  float dx = __fsub_rn(r0.x, qx);
  float dy = __fsub_rn(r0.y, qy);
  float dz = __fsub_rn(r0.z, qz);
  size_t qs = (size_t)b * NPOINT + qi;
  out[OFF_IDX + qs * NSAMPLE + s] = (float)p;  // idx stored as float32
  float* g = out + OFF_GXYZ + (qs * NSAMPLE + s) * 3;
  g[0] = dx;
  g[1] = dy;
  g[2] = dz;
  const float* row = base + (size_t)p * CH;
  float4 r1 = *reinterpret_cast<const float4*>(row + 4);
  float4 r2 = *reinterpret_cast<const float4*>(row + 8);
  float4 r3 = *reinterpret_cast<const float4*>(row + 12);
  float* np_ = out + OFF_NEWPTS + (qs * NSAMPLE + s) * CH;
  *reinterpret_cast<float4*>(np_ + 0) = make_float4(dx, dy, dz, r0.w);
  *reinterpret_cast<float4*>(np_ + 4) = r1;
  *reinterpret_cast<float4*>(np_ + 8) = r2;
  *reinterpret_cast<float4*>(np_ + 12) = r3;
}

__global__ __launch_bounds__(256) void ballq_kernel(
    const float* __restrict__ in, float* __restrict__ out) {
  const int lane = threadIdx.x & 63;
  const int qid = blockIdx.x * 4 + (threadIdx.x >> 6);
  const int b = qid >> 11;    // / NPOINT
  const int qi = qid & 2047;  // % NPOINT
  const float* base = in + (size_t)b * NPTS * CH;
  const float* q = out + OFF_NEWXYZ + ((size_t)b * NPOINT + qi) * 3;
  float qx = q[0], qy = q[1], qz = q[2];
  // Mirror reference: d2 = sum(q*q) + sum(p*p) - 2*(q . p)
  float qn = __fadd_rn(__fadd_rn(__fmul_rn(qx, qx), __fmul_rn(qy, qy)),
                       __fmul_rn(qz, qz));

  int cnt = 0;
  int first = 0;
  bool have_first = false;
  for (int chunk = 0; chunk < NPTS / 64 && cnt < NSAMPLE; ++chunk) {
    int p = chunk * 64 + lane;
    float4 r0 = *reinterpret_cast<const float4*>(base + (size_t)p * CH);
    float pn =
        __fadd_rn(__fadd_rn(__fmul_rn(r0.x, r0.x), __fmul_rn(r0.y, r0.y)),
                  __fmul_rn(r0.z, r0.z));
    float dot =
        __fadd_rn(__fadd_rn(__fmul_rn(qx, r0.x), __fmul_rn(qy, r0.y)),
                  __fmul_rn(qz, r0.z));
    float d2 = __fsub_rn(__fadd_rn(qn, pn), __fmul_rn(2.0f, dot));
    bool in_r = d2 < 1.0f;  // RADIUS^2
    unsigned long long mask = __ballot(in_r);
    if (!have_first && mask) {
      first = chunk * 64 + __builtin_ctzll(mask);
      have_first = true;
    }
    int pos = cnt + __popcll(mask & ((1ull << lane) - 1ull));
    if (in_r && pos < NSAMPLE) write_slot(out, base, b, qi, pos, p, r0, qx, qy, qz);
    cnt += __popcll(mask);
  }
  if (cnt < NSAMPLE) {
    // Pad remaining slots with the first in-radius index (reference fill rule).
    int s = cnt + lane;
    if (s < NSAMPLE) {
      float4 r0 = *reinterpret_cast<const float4*>(base + (size_t)first * CH);
      write_slot(out, base, b, qi, s, first, r0, qx, qy, qz);
    }
  }
}

extern "C" void kernel_launch(void* const* d_in, const int* in_sizes, int n_in,
                              void* d_out, int out_size, void* d_ws,
                              size_t ws_size, hipStream_t stream) {
  (void)in_sizes;
  (void)n_in;
  (void)out_size;
  (void)d_ws;
  (void)ws_size;
  const float* in = (const float*)d_in[0];
  float* out = (float*)d_out;
  fps_kernel<<<NB, FPS_THREADS, 0, stream>>>(in, out);
  ballq_kernel<<<(NB * NPOINT) / 4, 256, 0, stream>>>(in, out);
}